// Round 3
// baseline (420.312 us; speedup 1.0000x reference)
//
#include <hip/hip_runtime.h>

// Problem constants
#define N_     8
#define C_     16
#define T_     300
#define F_     257
#define TF_    (T_*F_)        // 77100
#define CTF_   (C_*TF_)       // 1233600
#define N2CTF_ (2*CTF_)       // per-batch stride in floats (re+im planes)

// K1 tiling
#define FT_    32             // f-tile width
#define NFT_   9              // ceil(257/32)
#define SROW_  34             // 32 y rows (c*2+plane) + 2 x rows (re,im) per staged t
#define SSTG_  (SROW_*32)     // floats per staged t = 1088
#define NTILE_ 10             // lower-triangle 4x4 tiles of the 16x16 Hermitian phi
#define PHIC_  (NTILE_*16)    // 160 float2 stored per (tc,n,f)

#define LOADC  7.0710678118654755e-04f   // 0.001/sqrt(2)

typedef float v2f __attribute__((ext_vector_type(2)));

__device__ __forceinline__ float2 cmul(float2 a, float2 b) {
  return make_float2(a.x*b.x - a.y*b.y, a.x*b.y + a.y*b.x);
}
__device__ __forceinline__ float2 cmulc(float2 a, float2 b) { // a * conj(b)
  return make_float2(a.x*b.x + a.y*b.y, a.y*b.x - a.x*b.y);
}
__device__ __forceinline__ float2 cdiv(float2 a, float2 b) {
  float inv = 1.0f / (b.x*b.x + b.y*b.y);
  return make_float2((a.x*b.x + a.y*b.y)*inv, (a.y*b.x - a.x*b.y)*inv);
}
__device__ __forceinline__ float2 cadd(float2 a, float2 b){ return make_float2(a.x+b.x, a.y+b.y); }
__device__ __forceinline__ float2 csub(float2 a, float2 b){ return make_float2(a.x-b.x, a.y-b.y); }

// Async global->LDS DMA, 4 B per lane. LDS dest is wave-uniform base + lane*4;
// global src is per-lane. (16-B width is unusable here: F=257 makes row bases
// misaligned mod 16 for 3 of 4 t's.)
__device__ __forceinline__ void gload4(const float* g, float* l) {
  __builtin_amdgcn_global_load_lds(
      (const __attribute__((address_space(1))) unsigned int*)g,
      (__attribute__((address_space(3))) unsigned int*)l, 4, 0, 0);
}

// ---------------------------------------------------------------------------
// K1 v8: Hermitian partial covariance + cross sums.
// grid (NFT_, TCP, N_), block 320 = 32 f-lanes x 10 lower-triangle groups.
// Structure = R1's proven v6 (double-buffered global_load_lds, ONE
// __syncthreads per stage, no inline asm -- R2's counted-vmcnt ring raised
// VGPR 96->128 with ~15 MB of symmetric spill traffic and cut residency to
// 2 blocks/CU; reverted). Delta vs v6: TS (t's per stage) is now a template
// param. TS=4 -> LDS = 2*4*34*32*4 = 34.8 KB -> 4 blocks/CU (was 43.5 KB ->
// 3), and VGPR 96 allows exactly 5 waves/SIMD = 4 blocks = 20 waves/CU.
// TCP=15 (TCH=20, NS=5) gives 1080 blocks = 4.2/CU to fill the capacity.
// Waves 0..TS-1 stage one t each (17 DMAs); wave 4 computes only.
// Hazards per stage s (one barrier): barrier waits vmcnt(0)+lgkmcnt(0), so
// (a) stage-s DMAs (issued after previous barrier) have landed block-wide,
// (b) all waves finished reading buf (s-1)&1 before issue(s+1) overwrites
//     buf (s+1)&1 ... which equals buf (s-1)&1. Same invariant as v6.
// ---------------------------------------------------------------------------
template<int TCH, int TS>
__global__ __launch_bounds__(320) void k1_cov(const float* __restrict__ mix,
                                              const float* __restrict__ tgt,
                                              float2* __restrict__ phi_pf,
                                              float2* __restrict__ syx_pf,
                                              float2* __restrict__ sy_pf,
                                              float2* __restrict__ sx_pf) {
  constexpr int SBUF = TS * SSTG_;
  __shared__ float ys[2 * SBUF];
  v2f* phi_p = (v2f*)phi_pf;
  v2f* syx_p = (v2f*)syx_pf;
  v2f* sy_p  = (v2f*)sy_pf;
  v2f* sx_p  = (v2f*)sx_pf;
  const int tid = threadIdx.x;
  const int ft = blockIdx.x, tc = blockIdx.y, n = blockIdx.z;
  const int fbase = ft * FT_;
  const int t0 = tc * TCH;
  const int fl = tid & 31;
  const int g  = tid >> 5;          // 0..9
  int ti = 0, tj = g;               // lower-triangle tile decode, ti>=tj
  while (tj > ti) { ++ti; tj -= ti; }
  const int c0 = ti * 4;
  const int d0 = tj * 4;
  const bool sThread = (tj == 0);   // tiles (0..3,0): c0 covers 0,4,8,12

  // staging decode: wave w stages t=w of each stage (w < TS); lane = plane*32+fl
  const int w     = tid >> 6;           // 0..4 (uniform per wave)
  const int plane = (tid >> 5) & 1;     // 0 = re, 1 = im
  const int f_ld  = min(fbase + fl, F_ - 1);   // clamped OOB f

  const float* mixN = mix + n * N2CTF_;
  const float* tgtN = tgt + n * N2CTF_;
  const float* ysrc = mixN + plane * CTF_ + (t0 + w) * F_ + f_ld;  // c=0, s=0
  const float* xsrc = tgtN + plane * CTF_ + (t0 + w) * F_ + f_ld;  // ref mic

  v2f acc[4][4];
  #pragma unroll
  for (int i = 0; i < 4; ++i)
    #pragma unroll
    for (int j = 0; j < 4; ++j) acc[i][j] = (v2f){0.f, 0.f};
  v2f syx[4], sy[4], sx = (v2f){0.f, 0.f};
  #pragma unroll
  for (int i = 0; i < 4; ++i) { syx[i] = (v2f){0.f,0.f}; sy[i] = (v2f){0.f,0.f}; }

  constexpr int NS = TCH / TS;
  static_assert(NS * TS == TCH, "TCH must be a multiple of TS");

  auto issue = [&](int stg) {
    if (w < TS) {
      float* dst = &ys[(stg & 1) * SBUF + w * SSTG_];
      const float* yp = ysrc + stg * (TS * F_);
      #pragma unroll
      for (int c = 0; c < 16; ++c) gload4(yp + c * TF_, dst + 2 * c * 32);
      gload4(xsrc + stg * (TS * F_), dst + 32 * 32);
    }
  };

  // prologue: stage 0 into buffer 0
  issue(0);

  for (int s = 0; s < NS; ++s) {
    __syncthreads();                 // vmcnt(0)+barrier: buf[s&1] ready block-wide
    if (s + 1 < NS) issue(s + 1);    // fills buf[(s+1)&1] while we compute buf[s&1]
    const float* bufc = &ys[(s & 1) * SBUF];
    #pragma unroll
    for (int tl = 0; tl < TS; ++tl) {
      const float* rt = bufc + tl * SSTG_;
      v2f a[4], bu[4], bv[4];
      #pragma unroll
      for (int i = 0; i < 4; ++i) {
        float re = rt[(2 * (c0 + i)) * 32 + fl];
        float im = rt[(2 * (c0 + i)) * 32 + 32 + fl];
        a[i] = (v2f){re, im};
      }
      #pragma unroll
      for (int j = 0; j < 4; ++j) {
        float re = rt[(2 * (d0 + j)) * 32 + fl];
        float im = rt[(2 * (d0 + j)) * 32 + 32 + fl];
        bu[j] = (v2f){re, -im};            // for y_c * conj(y_d)
        bv[j] = (v2f){im,  re};
      }
      #pragma unroll
      for (int i = 0; i < 4; ++i)
        #pragma unroll
        for (int j = 0; j < 4; ++j)
          acc[i][j] += a[i].x * bu[j] + a[i].y * bv[j];
      if (sThread) {
        float xre = rt[32 * 32 + fl];
        float xim = rt[33 * 32 + fl];
        v2f xu = (v2f){xre, -xim};
        v2f xw = (v2f){xim,  xre};
        #pragma unroll
        for (int i = 0; i < 4; ++i) {
          syx[i] += a[i].x * xu + a[i].y * xw;   // y_c * conj(x0)
          sy[i]  += a[i];
        }
        if (g == 0) sx += (v2f){xre, xim};
      }
    }
  }

  const int f = fbase + fl;
  if (f < F_) {
    const int tcn = tc * N_ + n;
    // tile g stored at offset g*16, row-major 4x4 -> 128 B contiguous/lane
    v2f* pb = phi_p + ((size_t)tcn * F_ + f) * PHIC_ + g * 16;
    #pragma unroll
    for (int i = 0; i < 4; ++i)
      #pragma unroll
      for (int j = 0; j < 4; ++j) pb[i * 4 + j] = acc[i][j];
    if (sThread) {
      v2f* s1 = syx_p + ((size_t)tcn * F_ + f) * C_ + c0;
      v2f* s2 = sy_p  + ((size_t)tcn * F_ + f) * C_ + c0;
      #pragma unroll
      for (int i = 0; i < 4; ++i) { s1[i] = syx[i]; s2[i] = sy[i]; }
      if (g == 0) sx_p[(size_t)tcn * F_ + f] = sx;
    }
  }
}

// ---------------------------------------------------------------------------
// K2 fused: reduction + rhs + in-block Gauss-Jordan solve.
// grid (F_, N_), block 256 = (i,j) of the 16x16 M. M never touches HBM.
// GJ: thread (i,j) owns M[i][j]; thread (i,15) also owns rhs M[i][16].
// ---------------------------------------------------------------------------
template<int TCP>
__global__ __launch_bounds__(256) void k2_fused(const float2* __restrict__ phi_p,
                                                const float2* __restrict__ syx_p,
                                                const float2* __restrict__ sy_p,
                                                const float2* __restrict__ sx_p,
                                                float* __restrict__ wre,
                                                float* __restrict__ wim) {
  __shared__ float2 ld_sy[TCP * N_ * C_];
  __shared__ float2 ld_syx[TCP * C_];
  __shared__ float2 ld_sx[TCP * N_];
  __shared__ float2 Msh[16 * 17];
  __shared__ float2 muB_s, sxO_s;
  const int f = blockIdx.x, n = blockIdx.y;
  const int tid = threadIdx.x;
  const int i = tid >> 4, j = tid & 15;

  // Hermitian mirror: (i,j) in lower tile (ti,tj) directly, else conj (j,i).
  const int ti = i >> 2, tj = j >> 2, ci = i & 3, cj = j & 3;
  int gL, cell; bool cj_flip;
  if (ti >= tj) { gL = ti * (ti + 1) / 2 + tj; cell = ci * 4 + cj; cj_flip = false; }
  else          { gL = tj * (tj + 1) / 2 + ti; cell = cj * 4 + ci; cj_flip = true; }
  const int off = gL * 16 + cell;

  float2 s = make_float2(0.f, 0.f);
  for (int tc = 0; tc < TCP; ++tc) {
    float2 v = phi_p[((size_t)(tc * N_ + n) * F_ + f) * PHIC_ + off];
    s.x += v.x; s.y += v.y;
  }
  if (cj_flip) s.y = -s.y;
  if (i == j) { s.x += (float)T_ * LOADC; s.y += (float)T_ * LOADC; }

  for (int idx = tid; idx < TCP * N_ * C_; idx += 256) {
    int tcn = idx >> 4, c = idx & 15;
    ld_sy[idx] = sy_p[((size_t)tcn * F_ + f) * C_ + c];
  }
  for (int idx = tid; idx < TCP * C_; idx += 256) {
    int tc = idx >> 4, c = idx & 15;
    ld_syx[idx] = syx_p[((size_t)(tc * N_ + n) * F_ + f) * C_ + c];
  }
  for (int idx = tid; idx < TCP * N_; idx += 256) {
    ld_sx[idx] = sx_p[(size_t)idx * F_ + f];
  }
  __syncthreads();   // uniform

  float2 muA_r = make_float2(0.f,0.f), ownY = make_float2(0.f,0.f), ownYX = make_float2(0.f,0.f);
  if (tid < 16) {
    float2 allY = make_float2(0.f,0.f);
    for (int tcn = 0; tcn < TCP * N_; ++tcn) allY = cadd(allY, ld_sy[tcn * C_ + tid]);
    for (int tc = 0; tc < TCP; ++tc) {
      ownY  = cadd(ownY,  ld_sy[(tc * N_ + n) * C_ + tid]);
      ownYX = cadd(ownYX, ld_syx[tc * C_ + tid]);
    }
    const float invNT = 1.0f / ((float)N_ * (float)T_);
    muA_r = make_float2(allY.x * invNT, allY.y * invNT);
  }
  if (tid == 16) {
    float2 own = make_float2(0.f,0.f), all = make_float2(0.f,0.f);
    for (int tc = 0; tc < TCP; ++tc)
      for (int nn = 0; nn < N_; ++nn) {
        float2 v = ld_sx[tc * N_ + nn];
        all = cadd(all, v);
        if (nn == n) own = cadd(own, v);
      }
    const float invNT = 1.0f / ((float)N_ * (float)T_);
    muB_s = make_float2(all.x * invNT, all.y * invNT);
    sxO_s = own;
  }
  __syncthreads();   // uniform: publish muB_s/sxO_s

  Msh[i * 17 + j] = s;
  if (tid < 16) {
    // rhs = S_yx - muA*conj(S_x_own) - conj(muB)*S_y_own + T*muA*conj(muB)
    float2 r = ownYX;
    r = csub(r, cmulc(muA_r, sxO_s));
    r = csub(r, cmulc(ownY, muB_s));
    float2 t3 = cmulc(muA_r, muB_s);
    r.x += (float)T_ * t3.x; r.y += (float)T_ * t3.y;
    Msh[tid * 17 + 16] = r;
  }
  __syncthreads();   // uniform: M assembled in LDS

  // Gauss-Jordan, no pivoting (diag-dominant). Same op order as verified k2b.
  for (int k = 0; k < 16; ++k) {
    float2 fac = cdiv(Msh[i * 17 + k], Msh[k * 17 + k]);
    __syncthreads();
    if (i != k) {
      Msh[i * 17 + j] = csub(Msh[i * 17 + j], cmul(fac, Msh[k * 17 + j]));
      if (j == 15) Msh[i * 17 + 16] = csub(Msh[i * 17 + 16], cmul(fac, Msh[k * 17 + 16]));
    }
    __syncthreads();
  }
  if (j == 0) {
    float2 wv = cdiv(Msh[i * 17 + 16], Msh[i * 17 + i]);
    wre[(n * C_ + i) * F_ + f] = wv.x;
    wim[(n * C_ + i) * F_ + f] = wv.y;
  }
}

// ---------------------------------------------------------------------------
// K3 v5: beamform, 2 t's per block. grid (T_/2, N_) = 1200 blocks x 320 thr
// (5 waves). f = tid single-pass. Unchanged this round.
// ---------------------------------------------------------------------------
__global__ __launch_bounds__(320) void k3_bf(const float* __restrict__ mix,
                                             const float* __restrict__ wre,
                                             const float* __restrict__ wim,
                                             float* __restrict__ out) {
  const int t0 = blockIdx.x * 2, n = blockIdx.y;
  const int f = threadIdx.x;
  if (f >= F_) return;
  const float* mixN = mix + n * N2CTF_;
  const float* wR = wre + n * C_ * F_;
  const float* wI = wim + n * C_ * F_;
  float* outN = out + n * 2 * TF_;
  float wr[16], wi[16];
  #pragma unroll
  for (int c = 0; c < 16; ++c) { wr[c] = wR[c * F_ + f]; wi[c] = wI[c * F_ + f]; }
  const float* yb = mixN + t0 * F_ + f;
  float xr0 = 0.f, xi0 = 0.f, xr1 = 0.f, xi1 = 0.f;
  #pragma unroll
  for (int c = 0; c < 16; ++c) {
    float yr0 = yb[c * TF_],      yi0 = yb[CTF_ + c * TF_];
    float yr1 = yb[c * TF_ + F_], yi1 = yb[CTF_ + c * TF_ + F_];
    xr0 += wr[c] * yr0 + wi[c] * yi0;   // conj(w)*y
    xi0 += wr[c] * yi0 - wi[c] * yr0;
    xr1 += wr[c] * yr1 + wi[c] * yi1;
    xi1 += wr[c] * yi1 - wi[c] * yr1;
  }
  outN[t0 * F_ + f] = xr0;
  outN[TF_ + t0 * F_ + f] = xi0;
  outN[(t0 + 1) * F_ + f] = xr1;
  outN[TF_ + (t0 + 1) * F_ + f] = xi1;
}

// ---------------------------------------------------------------------------
template<int TCP, int TS>
static void launch_all(const float* mix, const float* tgt, float* ws, float* out,
                       hipStream_t stream) {
  constexpr int TCH = T_ / TCP;
  static_assert(TCH * TCP == T_ && TCH % TS == 0, "chunking");
  float2* phi_p = (float2*)ws;
  float2* syx_p = phi_p + (size_t)TCP * N_ * F_ * PHIC_;
  float2* sy_p  = syx_p + (size_t)TCP * N_ * F_ * C_;
  float2* sx_p  = sy_p  + (size_t)TCP * N_ * F_ * C_;
  float*  wre   = (float*)(sx_p + (size_t)TCP * N_ * F_);
  float*  wim   = wre + N_ * C_ * F_;
  k1_cov<TCH, TS><<<dim3(NFT_, TCP, N_), dim3(320), 0, stream>>>(mix, tgt, phi_p, syx_p, sy_p, sx_p);
  k2_fused<TCP><<<dim3(F_, N_), dim3(256), 0, stream>>>(phi_p, syx_p, sy_p, sx_p, wre, wim);
  k3_bf<<<dim3(T_ / 2, N_), dim3(320), 0, stream>>>(mix, wre, wim, out);
}

static size_t ws_need_bytes(int tcp) {
  size_t fl2 = (size_t)tcp * N_ * F_ * (PHIC_ + 2 * C_ + 1);
  return fl2 * 8 + 2ull * N_ * C_ * F_ * 4;
}

extern "C" void kernel_launch(void* const* d_in, const int* in_sizes, int n_in,
                              void* d_out, int out_size, void* d_ws, size_t ws_size,
                              hipStream_t stream) {
  const float* mix = (const float*)d_in[0];
  const float* tgt = (const float*)d_in[1];
  // d_in[2] (steering_vector) is unused by the reference.
  float* out = (float*)d_out;
  float* ws  = (float*)d_ws;
  if (ws_size >= ws_need_bytes(15))      launch_all<15, 4>(mix, tgt, ws, out, stream);  // 4 blk/CU
  else if (ws_size >= ws_need_bytes(10)) launch_all<10, 5>(mix, tgt, ws, out, stream);  // R1 config
  else if (ws_size >= ws_need_bytes(2))  launch_all<2, 5>(mix, tgt, ws, out, stream);
  else                                   launch_all<1, 5>(mix, tgt, ws, out, stream);
}

// Round 4
// 269.111 us; speedup vs baseline: 1.5619x; 1.5619x over previous
//
#include <hip/hip_runtime.h>

// Problem constants
#define N_     8
#define C_     16
#define T_     300
#define F_     257
#define TF_    (T_*F_)        // 77100
#define CTF_   (C_*TF_)       // 1233600
#define N2CTF_ (2*CTF_)       // per-batch stride in floats (re+im planes)

// K1 tiling
#define FT_    32             // f-tile width
#define NFT_   9              // ceil(257/32)
#define NTILE_ 10             // lower-triangle 4x4 tiles of the 16x16 Hermitian phi
#define PHIC_  (NTILE_*16)    // 160 float2 stored per (tc,n,f)

#define LOADC  7.0710678118654755e-04f   // 0.001/sqrt(2)

typedef float v2f __attribute__((ext_vector_type(2)));

__device__ __forceinline__ float2 cmul(float2 a, float2 b) {
  return make_float2(a.x*b.x - a.y*b.y, a.x*b.y + a.y*b.x);
}
__device__ __forceinline__ float2 cmulc(float2 a, float2 b) { // a * conj(b)
  return make_float2(a.x*b.x + a.y*b.y, a.y*b.x - a.x*b.y);
}
__device__ __forceinline__ float2 cdiv(float2 a, float2 b) {
  float inv = 1.0f / (b.x*b.x + b.y*b.y);
  return make_float2((a.x*b.x + a.y*b.y)*inv, (a.y*b.x - a.x*b.y)*inv);
}
__device__ __forceinline__ float2 cadd(float2 a, float2 b){ return make_float2(a.x+b.x, a.y+b.y); }
__device__ __forceinline__ float2 csub(float2 a, float2 b){ return make_float2(a.x-b.x, a.y-b.y); }

// ---------------------------------------------------------------------------
// K1 v9: Hermitian partial covariance + cross sums -- DIRECT LOADS, NO LDS,
// NO BARRIERS. R1-R3 showed the cooperative-LDS pipeline is stuck at a ~60us
// local optimum (barrier duty-cycle) and every deepening attempt (R2 ring,
// R3 TS=4) blew up register allocation (VGPR 128 + hundreds of MB of scratch
// spill traffic). The in-block redundancy the LDS was sharing is only ~2.5x
// (80 row-reads/t vs 32 unique rows, 4 KB working set per t) -- L1 (32 KB/CU)
// absorbs it. So: each lane loads its own a/b rows straight from global;
// waves run fully decoupled; the compiler software-pipelines the loads.
//
// grid (NFT_, TCP, N_), block 320 = 32 f-lanes x 10 tile groups.
// Group->tile mapping puts the 4 DIAGONAL tiles (ti==tj, a==b) in g0..g3
// (waves 0-1) so they skip the b-row loads entirely -- 20% fewer VMEM
// instructions, uniform per wave (no divergence). Storage epilogue converts
// back to the canonical gL = ti*(ti+1)/2+tj offset, so K2 is unchanged.
// ---------------------------------------------------------------------------
template<int TCH>
__global__ __launch_bounds__(320) void k1_cov(const float* __restrict__ mix,
                                              const float* __restrict__ tgt,
                                              float2* __restrict__ phi_pf,
                                              float2* __restrict__ syx_pf,
                                              float2* __restrict__ sy_pf,
                                              float2* __restrict__ sx_pf) {
  v2f* phi_p = (v2f*)phi_pf;
  v2f* syx_p = (v2f*)syx_pf;
  v2f* sy_p  = (v2f*)sy_pf;
  v2f* sx_p  = (v2f*)sx_pf;
  const int tid = threadIdx.x;
  const int ft = blockIdx.x, tc = blockIdx.y, n = blockIdx.z;
  const int fbase = ft * FT_;
  const int t0 = tc * TCH;
  const int fl = tid & 31;
  const int g  = tid >> 5;          // 0..9

  // g0..g3: diagonal tiles (g,g). g4..g9: strict lower tiles in row-major order.
  int ti, tj;
  if (g < 4) { ti = g; tj = g; }
  else {
    int k = g - 4; ti = 1;
    while (k >= ti) { k -= ti; ++ti; }
    tj = k;
  }
  const int c0 = ti * 4;
  const int d0 = tj * 4;
  const bool DIAG = (g < 4);            // uniform per wave (w0:g0,g1 w1:g2,g3)
  const bool sThread = (tj == 0);       // c0 covers 0,4,8,12 across g0,g4,g5,g7

  const int f_ld = min(fbase + fl, F_ - 1);   // clamped OOB f (write-guarded)

  const float* yre = mix + n * N2CTF_;
  const float* yim = yre + CTF_;
  const float* xre = tgt + n * N2CTF_;
  const float* xim = xre + CTF_;

  const int obase = t0 * F_ + f_ld;

  v2f acc[4][4];
  #pragma unroll
  for (int i = 0; i < 4; ++i)
    #pragma unroll
    for (int j = 0; j < 4; ++j) acc[i][j] = (v2f){0.f, 0.f};
  v2f syx[4], sy[4], sx = (v2f){0.f, 0.f};
  #pragma unroll
  for (int i = 0; i < 4; ++i) { syx[i] = (v2f){0.f,0.f}; sy[i] = (v2f){0.f,0.f}; }

  #pragma unroll 2
  for (int t = 0; t < TCH; ++t) {
    const int o = obase + t * F_;
    v2f a[4], bu[4], bv[4];
    #pragma unroll
    for (int i = 0; i < 4; ++i) {
      const int ro = (c0 + i) * TF_ + o;
      a[i] = (v2f){yre[ro], yim[ro]};
    }
    if (DIAG) {
      #pragma unroll
      for (int j = 0; j < 4; ++j) {
        bu[j] = (v2f){a[j].x, -a[j].y};
        bv[j] = (v2f){a[j].y,  a[j].x};
      }
    } else {
      #pragma unroll
      for (int j = 0; j < 4; ++j) {
        const int ro = (d0 + j) * TF_ + o;
        float re = yre[ro], im = yim[ro];
        bu[j] = (v2f){re, -im};
        bv[j] = (v2f){im,  re};
      }
    }
    #pragma unroll
    for (int i = 0; i < 4; ++i)
      #pragma unroll
      for (int j = 0; j < 4; ++j)
        acc[i][j] += a[i].x * bu[j] + a[i].y * bv[j];   // y_c * conj(y_d)
    if (sThread) {
      float xr = xre[o], xi = xim[o];
      v2f xu = (v2f){xr, -xi};
      v2f xw = (v2f){xi,  xr};
      #pragma unroll
      for (int i = 0; i < 4; ++i) {
        syx[i] += a[i].x * xu + a[i].y * xw;   // y_c * conj(x0)
        sy[i]  += a[i];
      }
      if (g == 0) sx += (v2f){xr, xi};
    }
  }

  const int f = fbase + fl;
  if (f < F_) {
    const int tcn = tc * N_ + n;
    const int gstore = ti * (ti + 1) / 2 + tj;   // canonical offset K2 expects
    // tile stored at offset gstore*16, row-major 4x4 -> 128 B contiguous/lane
    v2f* pb = phi_p + ((size_t)tcn * F_ + f) * PHIC_ + gstore * 16;
    #pragma unroll
    for (int i = 0; i < 4; ++i)
      #pragma unroll
      for (int j = 0; j < 4; ++j) pb[i * 4 + j] = acc[i][j];
    if (sThread) {
      v2f* s1 = syx_p + ((size_t)tcn * F_ + f) * C_ + c0;
      v2f* s2 = sy_p  + ((size_t)tcn * F_ + f) * C_ + c0;
      #pragma unroll
      for (int i = 0; i < 4; ++i) { s1[i] = syx[i]; s2[i] = sy[i]; }
      if (g == 0) sx_p[(size_t)tcn * F_ + f] = sx;
    }
  }
}

// ---------------------------------------------------------------------------
// K2 fused: reduction + rhs + in-block Gauss-Jordan solve.
// grid (F_, N_), block 256 = (i,j) of the 16x16 M. M never touches HBM.
// ---------------------------------------------------------------------------
template<int TCP>
__global__ __launch_bounds__(256) void k2_fused(const float2* __restrict__ phi_p,
                                                const float2* __restrict__ syx_p,
                                                const float2* __restrict__ sy_p,
                                                const float2* __restrict__ sx_p,
                                                float* __restrict__ wre,
                                                float* __restrict__ wim) {
  __shared__ float2 ld_sy[TCP * N_ * C_];
  __shared__ float2 ld_syx[TCP * C_];
  __shared__ float2 ld_sx[TCP * N_];
  __shared__ float2 Msh[16 * 17];
  __shared__ float2 muB_s, sxO_s;
  const int f = blockIdx.x, n = blockIdx.y;
  const int tid = threadIdx.x;
  const int i = tid >> 4, j = tid & 15;

  // Hermitian mirror: (i,j) in lower tile (ti,tj) directly, else conj (j,i).
  const int ti = i >> 2, tj = j >> 2, ci = i & 3, cj = j & 3;
  int gL, cell; bool cj_flip;
  if (ti >= tj) { gL = ti * (ti + 1) / 2 + tj; cell = ci * 4 + cj; cj_flip = false; }
  else          { gL = tj * (tj + 1) / 2 + ti; cell = cj * 4 + ci; cj_flip = true; }
  const int off = gL * 16 + cell;

  float2 s = make_float2(0.f, 0.f);
  for (int tc = 0; tc < TCP; ++tc) {
    float2 v = phi_p[((size_t)(tc * N_ + n) * F_ + f) * PHIC_ + off];
    s.x += v.x; s.y += v.y;
  }
  if (cj_flip) s.y = -s.y;
  if (i == j) { s.x += (float)T_ * LOADC; s.y += (float)T_ * LOADC; }

  for (int idx = tid; idx < TCP * N_ * C_; idx += 256) {
    int tcn = idx >> 4, c = idx & 15;
    ld_sy[idx] = sy_p[((size_t)tcn * F_ + f) * C_ + c];
  }
  for (int idx = tid; idx < TCP * C_; idx += 256) {
    int tc = idx >> 4, c = idx & 15;
    ld_syx[idx] = syx_p[((size_t)(tc * N_ + n) * F_ + f) * C_ + c];
  }
  for (int idx = tid; idx < TCP * N_; idx += 256) {
    ld_sx[idx] = sx_p[(size_t)idx * F_ + f];
  }
  __syncthreads();   // uniform

  float2 muA_r = make_float2(0.f,0.f), ownY = make_float2(0.f,0.f), ownYX = make_float2(0.f,0.f);
  if (tid < 16) {
    float2 allY = make_float2(0.f,0.f);
    for (int tcn = 0; tcn < TCP * N_; ++tcn) allY = cadd(allY, ld_sy[tcn * C_ + tid]);
    for (int tc = 0; tc < TCP; ++tc) {
      ownY  = cadd(ownY,  ld_sy[(tc * N_ + n) * C_ + tid]);
      ownYX = cadd(ownYX, ld_syx[tc * C_ + tid]);
    }
    const float invNT = 1.0f / ((float)N_ * (float)T_);
    muA_r = make_float2(allY.x * invNT, allY.y * invNT);
  }
  if (tid == 16) {
    float2 own = make_float2(0.f,0.f), all = make_float2(0.f,0.f);
    for (int tc = 0; tc < TCP; ++tc)
      for (int nn = 0; nn < N_; ++nn) {
        float2 v = ld_sx[tc * N_ + nn];
        all = cadd(all, v);
        if (nn == n) own = cadd(own, v);
      }
    const float invNT = 1.0f / ((float)N_ * (float)T_);
    muB_s = make_float2(all.x * invNT, all.y * invNT);
    sxO_s = own;
  }
  __syncthreads();   // uniform: publish muB_s/sxO_s

  Msh[i * 17 + j] = s;
  if (tid < 16) {
    // rhs = S_yx - muA*conj(S_x_own) - conj(muB)*S_y_own + T*muA*conj(muB)
    float2 r = ownYX;
    r = csub(r, cmulc(muA_r, sxO_s));
    r = csub(r, cmulc(ownY, muB_s));
    float2 t3 = cmulc(muA_r, muB_s);
    r.x += (float)T_ * t3.x; r.y += (float)T_ * t3.y;
    Msh[tid * 17 + 16] = r;
  }
  __syncthreads();   // uniform: M assembled in LDS

  // Gauss-Jordan, no pivoting (diag-dominant). Same op order as verified k2b.
  for (int k = 0; k < 16; ++k) {
    float2 fac = cdiv(Msh[i * 17 + k], Msh[k * 17 + k]);
    __syncthreads();
    if (i != k) {
      Msh[i * 17 + j] = csub(Msh[i * 17 + j], cmul(fac, Msh[k * 17 + j]));
      if (j == 15) Msh[i * 17 + 16] = csub(Msh[i * 17 + 16], cmul(fac, Msh[k * 17 + 16]));
    }
    __syncthreads();
  }
  if (j == 0) {
    float2 wv = cdiv(Msh[i * 17 + 16], Msh[i * 17 + i]);
    wre[(n * C_ + i) * F_ + f] = wv.x;
    wim[(n * C_ + i) * F_ + f] = wv.y;
  }
}

// ---------------------------------------------------------------------------
// K3 v5: beamform, 2 t's per block. grid (T_/2, N_) = 1200 blocks x 320 thr
// (5 waves). f = tid single-pass. Unchanged this round.
// ---------------------------------------------------------------------------
__global__ __launch_bounds__(320) void k3_bf(const float* __restrict__ mix,
                                             const float* __restrict__ wre,
                                             const float* __restrict__ wim,
                                             float* __restrict__ out) {
  const int t0 = blockIdx.x * 2, n = blockIdx.y;
  const int f = threadIdx.x;
  if (f >= F_) return;
  const float* mixN = mix + n * N2CTF_;
  const float* wR = wre + n * C_ * F_;
  const float* wI = wim + n * C_ * F_;
  float* outN = out + n * 2 * TF_;
  float wr[16], wi[16];
  #pragma unroll
  for (int c = 0; c < 16; ++c) { wr[c] = wR[c * F_ + f]; wi[c] = wI[c * F_ + f]; }
  const float* yb = mixN + t0 * F_ + f;
  float xr0 = 0.f, xi0 = 0.f, xr1 = 0.f, xi1 = 0.f;
  #pragma unroll
  for (int c = 0; c < 16; ++c) {
    float yr0 = yb[c * TF_],      yi0 = yb[CTF_ + c * TF_];
    float yr1 = yb[c * TF_ + F_], yi1 = yb[CTF_ + c * TF_ + F_];
    xr0 += wr[c] * yr0 + wi[c] * yi0;   // conj(w)*y
    xi0 += wr[c] * yi0 - wi[c] * yr0;
    xr1 += wr[c] * yr1 + wi[c] * yi1;
    xi1 += wr[c] * yi1 - wi[c] * yr1;
  }
  outN[t0 * F_ + f] = xr0;
  outN[TF_ + t0 * F_ + f] = xi0;
  outN[(t0 + 1) * F_ + f] = xr1;
  outN[TF_ + (t0 + 1) * F_ + f] = xi1;
}

// ---------------------------------------------------------------------------
template<int TCP>
static void launch_all(const float* mix, const float* tgt, float* ws, float* out,
                       hipStream_t stream) {
  constexpr int TCH = T_ / TCP;
  static_assert(TCH * TCP == T_, "chunking");
  float2* phi_p = (float2*)ws;
  float2* syx_p = phi_p + (size_t)TCP * N_ * F_ * PHIC_;
  float2* sy_p  = syx_p + (size_t)TCP * N_ * F_ * C_;
  float2* sx_p  = sy_p  + (size_t)TCP * N_ * F_ * C_;
  float*  wre   = (float*)(sx_p + (size_t)TCP * N_ * F_);
  float*  wim   = wre + N_ * C_ * F_;
  k1_cov<TCH><<<dim3(NFT_, TCP, N_), dim3(320), 0, stream>>>(mix, tgt, phi_p, syx_p, sy_p, sx_p);
  k2_fused<TCP><<<dim3(F_, N_), dim3(256), 0, stream>>>(phi_p, syx_p, sy_p, sx_p, wre, wim);
  k3_bf<<<dim3(T_ / 2, N_), dim3(320), 0, stream>>>(mix, wre, wim, out);
}

static size_t ws_need_bytes(int tcp) {
  size_t fl2 = (size_t)tcp * N_ * F_ * (PHIC_ + 2 * C_ + 1);
  return fl2 * 8 + 2ull * N_ * C_ * F_ * 4;
}

extern "C" void kernel_launch(void* const* d_in, const int* in_sizes, int n_in,
                              void* d_out, int out_size, void* d_ws, size_t ws_size,
                              hipStream_t stream) {
  const float* mix = (const float*)d_in[0];
  const float* tgt = (const float*)d_in[1];
  // d_in[2] (steering_vector) is unused by the reference.
  float* out = (float*)d_out;
  float* ws  = (float*)d_ws;
  if (ws_size >= ws_need_bytes(10))     launch_all<10>(mix, tgt, ws, out, stream);
  else if (ws_size >= ws_need_bytes(2)) launch_all<2>(mix, tgt, ws, out, stream);
  else                                  launch_all<1>(mix, tgt, ws, out, stream);
}

// Round 5
// 227.560 us; speedup vs baseline: 1.8470x; 1.1826x over previous
//
#include <hip/hip_runtime.h>

// Problem constants
#define N_     8
#define C_     16
#define T_     300
#define F_     257
#define TF_    (T_*F_)        // 77100
#define CTF_   (C_*TF_)       // 1233600
#define N2CTF_ (2*CTF_)       // per-batch stride in floats (re+im planes)

// K1 tiling
#define FT_    32             // f-tile width
#define NFT_   9              // ceil(257/32)
#define TS_    5              // t's staged per LDS stage (== waves/block)
#define SROW_  34             // 32 y rows (c*2+plane) + 2 x rows (re,im)
#define SSTG_  (SROW_*32)     // floats per staged t = 1088
#define SBUF_  (TS_*SSTG_)    // floats per buffer = 5440 (21.75 KB); x2 = 43.5 KB
#define NTILE_ 10             // lower-triangle 4x4 tiles of the 16x16 Hermitian phi
#define PHIC_  (NTILE_*16)    // 160 float2 stored per (tc,n,f)

#define LOADC  7.0710678118654755e-04f   // 0.001/sqrt(2)

typedef float v2f __attribute__((ext_vector_type(2)));

__device__ __forceinline__ float2 cmul(float2 a, float2 b) {
  return make_float2(a.x*b.x - a.y*b.y, a.x*b.y + a.y*b.x);
}
__device__ __forceinline__ float2 cmulc(float2 a, float2 b) { // a * conj(b)
  return make_float2(a.x*b.x + a.y*b.y, a.y*b.x - a.x*b.y);
}
__device__ __forceinline__ float2 cdiv(float2 a, float2 b) {
  float inv = 1.0f / (b.x*b.x + b.y*b.y);
  return make_float2((a.x*b.x + a.y*b.y)*inv, (a.y*b.x - a.x*b.y)*inv);
}
__device__ __forceinline__ float2 cadd(float2 a, float2 b){ return make_float2(a.x+b.x, a.y+b.y); }
__device__ __forceinline__ float2 csub(float2 a, float2 b){ return make_float2(a.x-b.x, a.y-b.y); }

// Async global->LDS DMA, 4 B per lane. LDS dest is wave-uniform base + lane*4;
// global src is per-lane.
__device__ __forceinline__ void gload4(const float* g, float* l) {
  __builtin_amdgcn_global_load_lds(
      (const __attribute__((address_space(1))) unsigned int*)g,
      (__attribute__((address_space(3))) unsigned int*)l, 4, 0, 0);
}

// ---------------------------------------------------------------------------
// K1 v6 (EXACT R1 restore -- measured 60.0-60.4 us, VGPR 96, zero spill).
// grid (NFT_, TCP, N_), block 320 = 32 f-lanes x 10 lower-triangle groups.
// Double-buffered global_load_lds staging, ONE __syncthreads per stage
// (implicit vmcnt(0)+lgkmcnt(0) drain at the barrier). Per-stage hazard:
// barrier at top of iter s guarantees (a) stage-s DMAs landed block-wide,
// (b) all waves finished computing stage s-1, so issue(s+1) may overwrite
// buf[(s+1)&1] == buf[(s-1)&1].
// History: R2 counted-vmcnt ring (VGPR 128, spills, 82us) and R3 TS=4
// (VGPR 128, 580 MB scratch traffic, 261us) and R4 direct-load (no MLP,
// 110us) all lost to this structure. Do not deepen the pipeline.
// ---------------------------------------------------------------------------
template<int TCH>
__global__ __launch_bounds__(320) void k1_cov(const float* __restrict__ mix,
                                              const float* __restrict__ tgt,
                                              float2* __restrict__ phi_pf,
                                              float2* __restrict__ syx_pf,
                                              float2* __restrict__ sy_pf,
                                              float2* __restrict__ sx_pf) {
  __shared__ float ys[2 * SBUF_];
  v2f* phi_p = (v2f*)phi_pf;
  v2f* syx_p = (v2f*)syx_pf;
  v2f* sy_p  = (v2f*)sy_pf;
  v2f* sx_p  = (v2f*)sx_pf;
  const int tid = threadIdx.x;
  const int ft = blockIdx.x, tc = blockIdx.y, n = blockIdx.z;
  const int fbase = ft * FT_;
  const int t0 = tc * TCH;
  const int fl = tid & 31;
  const int g  = tid >> 5;          // 0..9
  int ti = 0, tj = g;               // lower-triangle tile decode, ti>=tj
  while (tj > ti) { ++ti; tj -= ti; }
  const int c0 = ti * 4;
  const int d0 = tj * 4;
  const bool sThread = (tj == 0);   // tiles (0..3,0): c0 covers 0,4,8,12

  // staging decode: wave w stages ts=w; lane = plane*32 + fl
  const int w     = tid >> 6;           // 0..4 (uniform per wave)
  const int plane = (tid >> 5) & 1;     // 0 = re, 1 = im
  const int f_ld  = min(fbase + fl, F_ - 1);   // clamped OOB f

  const float* mixN = mix + n * N2CTF_;
  const float* tgtN = tgt + n * N2CTF_;
  const float* ysrc = mixN + plane * CTF_ + (t0 + w) * F_ + f_ld;  // c=0, s=0
  const float* xsrc = tgtN + plane * CTF_ + (t0 + w) * F_ + f_ld;  // ref mic

  v2f acc[4][4];
  #pragma unroll
  for (int i = 0; i < 4; ++i)
    #pragma unroll
    for (int j = 0; j < 4; ++j) acc[i][j] = (v2f){0.f, 0.f};
  v2f syx[4], sy[4], sx = (v2f){0.f, 0.f};
  #pragma unroll
  for (int i = 0; i < 4; ++i) { syx[i] = (v2f){0.f,0.f}; sy[i] = (v2f){0.f,0.f}; }

  constexpr int NS = TCH / TS_;
  static_assert(NS * TS_ == TCH, "TCH must be a multiple of TS_");

  // prologue: issue stage-0 DMA into buffer 0
  {
    float* dst = &ys[w * SSTG_];
    #pragma unroll
    for (int c = 0; c < 16; ++c) gload4(ysrc + c * TF_, dst + 2 * c * 32);
    gload4(xsrc, dst + 32 * 32);
  }

  for (int s = 0; s < NS; ++s) {
    __syncthreads();                 // vmcnt(0)+barrier: buf[s&1] ready everywhere
    if (s + 1 < NS) {                // issue next-stage DMA (drains at next barrier)
      float* dst = &ys[((s + 1) & 1) * SBUF_ + w * SSTG_];
      const float* yp = ysrc + (s + 1) * (TS_ * F_);
      #pragma unroll
      for (int c = 0; c < 16; ++c) gload4(yp + c * TF_, dst + 2 * c * 32);
      gload4(xsrc + (s + 1) * (TS_ * F_), dst + 32 * 32);
    }
    const float* bufc = &ys[(s & 1) * SBUF_];
    #pragma unroll
    for (int tl = 0; tl < TS_; ++tl) {
      const float* rt = bufc + tl * SSTG_;
      v2f a[4], bu[4], bv[4];
      #pragma unroll
      for (int i = 0; i < 4; ++i) {
        float re = rt[(2 * (c0 + i)) * 32 + fl];
        float im = rt[(2 * (c0 + i)) * 32 + 32 + fl];
        a[i] = (v2f){re, im};
      }
      #pragma unroll
      for (int j = 0; j < 4; ++j) {
        float re = rt[(2 * (d0 + j)) * 32 + fl];
        float im = rt[(2 * (d0 + j)) * 32 + 32 + fl];
        bu[j] = (v2f){re, -im};            // for y_c * conj(y_d)
        bv[j] = (v2f){im,  re};
      }
      #pragma unroll
      for (int i = 0; i < 4; ++i)
        #pragma unroll
        for (int j = 0; j < 4; ++j)
          acc[i][j] += a[i].x * bu[j] + a[i].y * bv[j];
      if (sThread) {
        float xre = rt[32 * 32 + fl];
        float xim = rt[33 * 32 + fl];
        v2f xu = (v2f){xre, -xim};
        v2f xw = (v2f){xim,  xre};
        #pragma unroll
        for (int i = 0; i < 4; ++i) {
          syx[i] += a[i].x * xu + a[i].y * xw;   // y_c * conj(x0)
          sy[i]  += a[i];
        }
        if (g == 0) sx += (v2f){xre, xim};
      }
    }
  }

  const int f = fbase + fl;
  if (f < F_) {
    const int tcn = tc * N_ + n;
    // tile g stored at offset g*16, row-major 4x4 -> 128 B contiguous/lane
    v2f* pb = phi_p + ((size_t)tcn * F_ + f) * PHIC_ + g * 16;
    #pragma unroll
    for (int i = 0; i < 4; ++i)
      #pragma unroll
      for (int j = 0; j < 4; ++j) pb[i * 4 + j] = acc[i][j];
    if (sThread) {
      v2f* s1 = syx_p + ((size_t)tcn * F_ + f) * C_ + c0;
      v2f* s2 = sy_p  + ((size_t)tcn * F_ + f) * C_ + c0;
      #pragma unroll
      for (int i = 0; i < 4; ++i) { s1[i] = syx[i]; s2[i] = sy[i]; }
      if (g == 0) sx_p[(size_t)tcn * F_ + f] = sx;
    }
  }
}

// ---------------------------------------------------------------------------
// K2 fused: reduction + rhs + in-block Gauss-Jordan solve.
// grid (F_, N_), block 256 = (i,j) of the 16x16 M. M never touches HBM.
// Verified (absmax pass) in R2/R3/R4.
// ---------------------------------------------------------------------------
template<int TCP>
__global__ __launch_bounds__(256) void k2_fused(const float2* __restrict__ phi_p,
                                                const float2* __restrict__ syx_p,
                                                const float2* __restrict__ sy_p,
                                                const float2* __restrict__ sx_p,
                                                float* __restrict__ wre,
                                                float* __restrict__ wim) {
  __shared__ float2 ld_sy[TCP * N_ * C_];
  __shared__ float2 ld_syx[TCP * C_];
  __shared__ float2 ld_sx[TCP * N_];
  __shared__ float2 Msh[16 * 17];
  __shared__ float2 muB_s, sxO_s;
  const int f = blockIdx.x, n = blockIdx.y;
  const int tid = threadIdx.x;
  const int i = tid >> 4, j = tid & 15;

  // Hermitian mirror: (i,j) in lower tile (ti,tj) directly, else conj (j,i).
  const int ti = i >> 2, tj = j >> 2, ci = i & 3, cj = j & 3;
  int gL, cell; bool cj_flip;
  if (ti >= tj) { gL = ti * (ti + 1) / 2 + tj; cell = ci * 4 + cj; cj_flip = false; }
  else          { gL = tj * (tj + 1) / 2 + ti; cell = cj * 4 + ci; cj_flip = true; }
  const int off = gL * 16 + cell;

  float2 s = make_float2(0.f, 0.f);
  for (int tc = 0; tc < TCP; ++tc) {
    float2 v = phi_p[((size_t)(tc * N_ + n) * F_ + f) * PHIC_ + off];
    s.x += v.x; s.y += v.y;
  }
  if (cj_flip) s.y = -s.y;
  if (i == j) { s.x += (float)T_ * LOADC; s.y += (float)T_ * LOADC; }

  for (int idx = tid; idx < TCP * N_ * C_; idx += 256) {
    int tcn = idx >> 4, c = idx & 15;
    ld_sy[idx] = sy_p[((size_t)tcn * F_ + f) * C_ + c];
  }
  for (int idx = tid; idx < TCP * C_; idx += 256) {
    int tc = idx >> 4, c = idx & 15;
    ld_syx[idx] = syx_p[((size_t)(tc * N_ + n) * F_ + f) * C_ + c];
  }
  for (int idx = tid; idx < TCP * N_; idx += 256) {
    ld_sx[idx] = sx_p[(size_t)idx * F_ + f];
  }
  __syncthreads();   // uniform

  float2 muA_r = make_float2(0.f,0.f), ownY = make_float2(0.f,0.f), ownYX = make_float2(0.f,0.f);
  if (tid < 16) {
    float2 allY = make_float2(0.f,0.f);
    for (int tcn = 0; tcn < TCP * N_; ++tcn) allY = cadd(allY, ld_sy[tcn * C_ + tid]);
    for (int tc = 0; tc < TCP; ++tc) {
      ownY  = cadd(ownY,  ld_sy[(tc * N_ + n) * C_ + tid]);
      ownYX = cadd(ownYX, ld_syx[tc * C_ + tid]);
    }
    const float invNT = 1.0f / ((float)N_ * (float)T_);
    muA_r = make_float2(allY.x * invNT, allY.y * invNT);
  }
  if (tid == 16) {
    float2 own = make_float2(0.f,0.f), all = make_float2(0.f,0.f);
    for (int tc = 0; tc < TCP; ++tc)
      for (int nn = 0; nn < N_; ++nn) {
        float2 v = ld_sx[tc * N_ + nn];
        all = cadd(all, v);
        if (nn == n) own = cadd(own, v);
      }
    const float invNT = 1.0f / ((float)N_ * (float)T_);
    muB_s = make_float2(all.x * invNT, all.y * invNT);
    sxO_s = own;
  }
  __syncthreads();   // uniform: publish muB_s/sxO_s

  Msh[i * 17 + j] = s;
  if (tid < 16) {
    // rhs = S_yx - muA*conj(S_x_own) - conj(muB)*S_y_own + T*muA*conj(muB)
    float2 r = ownYX;
    r = csub(r, cmulc(muA_r, sxO_s));
    r = csub(r, cmulc(ownY, muB_s));
    float2 t3 = cmulc(muA_r, muB_s);
    r.x += (float)T_ * t3.x; r.y += (float)T_ * t3.y;
    Msh[tid * 17 + 16] = r;
  }
  __syncthreads();   // uniform: M assembled in LDS

  // Gauss-Jordan, no pivoting (diag-dominant). Same op order as verified k2b.
  for (int k = 0; k < 16; ++k) {
    float2 fac = cdiv(Msh[i * 17 + k], Msh[k * 17 + k]);
    __syncthreads();
    if (i != k) {
      Msh[i * 17 + j] = csub(Msh[i * 17 + j], cmul(fac, Msh[k * 17 + j]));
      if (j == 15) Msh[i * 17 + 16] = csub(Msh[i * 17 + 16], cmul(fac, Msh[k * 17 + 16]));
    }
    __syncthreads();
  }
  if (j == 0) {
    float2 wv = cdiv(Msh[i * 17 + 16], Msh[i * 17 + i]);
    wre[(n * C_ + i) * F_ + f] = wv.x;
    wim[(n * C_ + i) * F_ + f] = wv.y;
  }
}

// ---------------------------------------------------------------------------
// K3 v5: beamform, 2 t's per block. grid (T_/2, N_) = 1200 blocks x 320 thr
// (5 waves). f = tid single-pass. Unchanged (isolation: diagnostic round).
// ---------------------------------------------------------------------------
__global__ __launch_bounds__(320) void k3_bf(const float* __restrict__ mix,
                                             const float* __restrict__ wre,
                                             const float* __restrict__ wim,
                                             float* __restrict__ out) {
  const int t0 = blockIdx.x * 2, n = blockIdx.y;
  const int f = threadIdx.x;
  if (f >= F_) return;
  const float* mixN = mix + n * N2CTF_;
  const float* wR = wre + n * C_ * F_;
  const float* wI = wim + n * C_ * F_;
  float* outN = out + n * 2 * TF_;
  float wr[16], wi[16];
  #pragma unroll
  for (int c = 0; c < 16; ++c) { wr[c] = wR[c * F_ + f]; wi[c] = wI[c * F_ + f]; }
  const float* yb = mixN + t0 * F_ + f;
  float xr0 = 0.f, xi0 = 0.f, xr1 = 0.f, xi1 = 0.f;
  #pragma unroll
  for (int c = 0; c < 16; ++c) {
    float yr0 = yb[c * TF_],      yi0 = yb[CTF_ + c * TF_];
    float yr1 = yb[c * TF_ + F_], yi1 = yb[CTF_ + c * TF_ + F_];
    xr0 += wr[c] * yr0 + wi[c] * yi0;   // conj(w)*y
    xi0 += wr[c] * yi0 - wi[c] * yr0;
    xr1 += wr[c] * yr1 + wi[c] * yi1;
    xi1 += wr[c] * yi1 - wi[c] * yr1;
  }
  outN[t0 * F_ + f] = xr0;
  outN[TF_ + t0 * F_ + f] = xi0;
  outN[(t0 + 1) * F_ + f] = xr1;
  outN[TF_ + (t0 + 1) * F_ + f] = xi1;
}

// ---------------------------------------------------------------------------
template<int TCP>
static void launch_all(const float* mix, const float* tgt, float* ws, float* out,
                       hipStream_t stream) {
  constexpr int TCH = T_ / TCP;
  static_assert(TCH * TCP == T_ && TCH % TS_ == 0, "chunking");
  float2* phi_p = (float2*)ws;
  float2* syx_p = phi_p + (size_t)TCP * N_ * F_ * PHIC_;
  float2* sy_p  = syx_p + (size_t)TCP * N_ * F_ * C_;
  float2* sx_p  = sy_p  + (size_t)TCP * N_ * F_ * C_;
  float*  wre   = (float*)(sx_p + (size_t)TCP * N_ * F_);
  float*  wim   = wre + N_ * C_ * F_;
  k1_cov<TCH><<<dim3(NFT_, TCP, N_), dim3(320), 0, stream>>>(mix, tgt, phi_p, syx_p, sy_p, sx_p);
  k2_fused<TCP><<<dim3(F_, N_), dim3(256), 0, stream>>>(phi_p, syx_p, sy_p, sx_p, wre, wim);
  k3_bf<<<dim3(T_ / 2, N_), dim3(320), 0, stream>>>(mix, wre, wim, out);
}

static size_t ws_need_bytes(int tcp) {
  size_t fl2 = (size_t)tcp * N_ * F_ * (PHIC_ + 2 * C_ + 1);
  return fl2 * 8 + 2ull * N_ * C_ * F_ * 4;
}

extern "C" void kernel_launch(void* const* d_in, const int* in_sizes, int n_in,
                              void* d_out, int out_size, void* d_ws, size_t ws_size,
                              hipStream_t stream) {
  const float* mix = (const float*)d_in[0];
  const float* tgt = (const float*)d_in[1];
  // d_in[2] (steering_vector) is unused by the reference.
  float* out = (float*)d_out;
  float* ws  = (float*)d_ws;
  if (ws_size >= ws_need_bytes(12))      launch_all<12>(mix, tgt, ws, out, stream);  // R1 config
  else if (ws_size >= ws_need_bytes(10)) launch_all<10>(mix, tgt, ws, out, stream);
  else if (ws_size >= ws_need_bytes(2))  launch_all<2>(mix, tgt, ws, out, stream);
  else                                   launch_all<1>(mix, tgt, ws, out, stream);
}